// Round 1
// baseline (1261.750 us; speedup 1.0000x reference)
//
#include <hip/hip_runtime.h>
#include <stdint.h>

#define B_ 2
#define T_ 2048
#define D_ 1024
#define DI_ 2048
#define DS_ 16
#define MROWS (B_*T_)

typedef unsigned short u16;
typedef __attribute__((ext_vector_type(4))) float f32x4;
typedef __attribute__((ext_vector_type(8))) short short8;
typedef __attribute__((ext_vector_type(4))) unsigned short u16x4;

__device__ __forceinline__ float bf2f(u16 u) {
    union { uint32_t i; float f; } v; v.i = ((uint32_t)u) << 16; return v.f;
}
__device__ __forceinline__ u16 f2bf(float f) {
    union { float f; uint32_t i; } v; v.f = f;
    uint32_t r = v.i + 0x7fff + ((v.i >> 16) & 1);
    return (u16)(r >> 16);
}

// ---------------- f32 -> bf16 convert (vectorized x4) ----------------
__global__ __launch_bounds__(256) void cvt_kernel(const float* __restrict__ in,
                                                  u16* __restrict__ out, int n4) {
    int i = blockIdx.x * 256 + threadIdx.x;
    if (i < n4) {
        float4 v = ((const float4*)in)[i];
        u16x4 o;
        o.x = f2bf(v.x); o.y = f2bf(v.y); o.z = f2bf(v.z); o.w = f2bf(v.w);
        ((u16x4*)out)[i] = o;
    }
}

// ---------------- bt-GEMM: out[m,n] = sum_k A[m,k] * W[n,k] ----------------
// A: M x K bf16 row-major, W: N x K bf16 row-major. 128x128 tile, BK=32,
// 4 waves each computing 64x64 via 4x4 grid of 16x16x32 MFMA fragments.
#define EPI_BF   0   // store bf16, no epilogue
#define EPI_SILU 1   // silu, store bf16
#define EPI_SP   2   // +b1[n]+b2[n], softplus, store bf16
#define EPI_F32  3   // store f32

template<int EPI>
__global__ __launch_bounds__(256) void gemm_bt(
    const u16* __restrict__ A, const u16* __restrict__ W,
    void* __restrict__ outv, int M, int N, int K,
    const float* __restrict__ b1, const float* __restrict__ b2) {
    __shared__ u16 lA[128 * 32];
    __shared__ u16 lB[128 * 32];
    const int tid  = threadIdx.x;
    const int lane = tid & 63;
    const int wave = tid >> 6;
    const int wr = wave >> 1, wc = wave & 1;
    const int m0 = blockIdx.y * 128, n0 = blockIdx.x * 128;

    f32x4 acc[4][4];
#pragma unroll
    for (int i = 0; i < 4; ++i)
#pragma unroll
        for (int j = 0; j < 4; ++j) acc[i][j] = (f32x4){0.f, 0.f, 0.f, 0.f};

    const int lrow = tid >> 2;      // 0..63
    const int lseg = tid & 3;       // 16B segment within 64B row

    for (int k0 = 0; k0 < K; k0 += 32) {
        __syncthreads();
#pragma unroll
        for (int it = 0; it < 2; ++it) {
            int row = it * 64 + lrow;
            const u16* sa = A + (size_t)(m0 + row) * K + k0 + lseg * 8;
            const u16* sw = W + (size_t)(n0 + row) * K + k0 + lseg * 8;
            __builtin_amdgcn_global_load_lds(
                (const __attribute__((address_space(1))) void*)sa,
                (__attribute__((address_space(3))) void*)(lA + row * 32 + lseg * 8),
                16, 0, 0);
            __builtin_amdgcn_global_load_lds(
                (const __attribute__((address_space(1))) void*)sw,
                (__attribute__((address_space(3))) void*)(lB + row * 32 + lseg * 8),
                16, 0, 0);
        }
        __syncthreads();

        const int fr = lane & 15, ks = lane >> 4;
        short8 af[4], bfr[4];
#pragma unroll
        for (int i = 0; i < 4; ++i) {
            af[i]  = *(const short8*)(lA + (wr * 64 + i * 16 + fr) * 32 + ks * 8);
            bfr[i] = *(const short8*)(lB + (wc * 64 + i * 16 + fr) * 32 + ks * 8);
        }
#pragma unroll
        for (int i = 0; i < 4; ++i)
#pragma unroll
            for (int j = 0; j < 4; ++j)
                acc[i][j] = __builtin_amdgcn_mfma_f32_16x16x32_bf16(
                    af[i], bfr[j], acc[i][j], 0, 0, 0);
    }

    // epilogue: D element (reg r): row = (lane>>4)*4 + r, col = lane&15
    const int fr = lane & 15, fq = lane >> 4;
#pragma unroll
    for (int i = 0; i < 4; ++i)
#pragma unroll
        for (int j = 0; j < 4; ++j) {
            int gn = n0 + wc * 64 + j * 16 + fr;
#pragma unroll
            for (int r = 0; r < 4; ++r) {
                int gm = m0 + wr * 64 + i * 16 + fq * 4 + r;
                float v = acc[i][j][r];
                if (EPI == EPI_SILU) v = v / (1.f + __expf(-v));
                if (EPI == EPI_SP) {
                    v += b1[gn] + b2[gn];
                    v = (v > 20.f) ? v : log1pf(__expf(v));
                }
                if (EPI == EPI_F32)
                    ((float*)outv)[(size_t)gm * N + gn] = v;
                else
                    ((u16*)outv)[(size_t)gm * N + gn] = f2bf(v);
            }
        }
}

// ---------------- Bm / C projections (N=16 each, fp32) ----------------
__global__ __launch_bounds__(256) void bc_kernel(
    const float* __restrict__ x, const float* __restrict__ WB,
    const float* __restrict__ WC, float* __restrict__ Bm, float* __restrict__ Cm) {
    __shared__ float xs[32][65];
    __shared__ float ws[32][65];
    int m0 = blockIdx.x * 32;
    int tid = threadIdx.x;
    int o = tid & 31, mg = tid >> 5;
    float acc[4] = {0.f, 0.f, 0.f, 0.f};
    for (int k0 = 0; k0 < D_; k0 += 64) {
        __syncthreads();
#pragma unroll
        for (int j = 0; j < 8; ++j) {
            int f = j * 256 + tid;
            int r = f >> 6, kk = f & 63;
            xs[r][kk] = x[(size_t)(m0 + r) * D_ + k0 + kk];
            ws[r][kk] = (r < 16) ? WB[(size_t)r * D_ + k0 + kk]
                                 : WC[(size_t)(r - 16) * D_ + k0 + kk];
        }
        __syncthreads();
#pragma unroll 8
        for (int kk = 0; kk < 64; ++kk) {
            float wv = ws[o][kk];
#pragma unroll
            for (int r = 0; r < 4; ++r)
                acc[r] = fmaf(xs[mg * 4 + r][kk], wv, acc[r]);
        }
    }
#pragma unroll
    for (int r = 0; r < 4; ++r) {
        int m = m0 + mg * 4 + r;
        if (o < 16) Bm[(size_t)m * DS_ + o] = acc[r];
        else        Cm[(size_t)m * DS_ + (o - 16)] = acc[r];
    }
}

// ---------------- sequential scan: 1 thread per (b,d,s) ----------------
__global__ __launch_bounds__(256) void scan_kernel(
    const u16* __restrict__ dt, const u16* __restrict__ xi,
    const float* __restrict__ Bm, const float* __restrict__ Cm,
    const float* __restrict__ A_log, u16* __restrict__ so,
    float* __restrict__ st_out) {
    int b  = blockIdx.x >> 7;            // 128 blocks per batch
    int d0 = (blockIdx.x & 127) << 4;    // 16 d per block
    int tid = threadIdx.x;
    int s = tid & 15, dl = tid >> 4;
    int d = d0 + dl;
    float A2 = -0.5f * expf(A_log[(size_t)d * DS_ + s]);
    size_t tb = (size_t)b * T_;
    const u16* dtp = dt + tb * DI_ + d;
    const u16* xip = xi + tb * DI_ + d;
    const float* bp = Bm + tb * DS_ + s;
    const float* cp = Cm + tb * DS_ + s;
    u16* sop = so + tb * DI_ + d;
    float st = 0.f;
#pragma unroll 4
    for (int t = 0; t < T_; ++t) {
        float dtv = bf2f(dtp[(size_t)t * DI_]);
        float xiv = bf2f(xip[(size_t)t * DI_]);
        float bv  = bp[(size_t)t * DS_];
        float cv  = cp[(size_t)t * DS_];
        float h   = dtv * A2;                       // 0.5*dt*A
        float inv = __builtin_amdgcn_rcpf(1.f - h);
        float abar = (1.f + h) * inv;
        float u   = (dtv * inv) * (bv * xiv);       // B_bar * Bt * xt
        st = fmaf(abar, st, u);
        float p = st * cv;
        p += __shfl_xor(p, 1, 16);
        p += __shfl_xor(p, 2, 16);
        p += __shfl_xor(p, 4, 16);
        p += __shfl_xor(p, 8, 16);
        if (s == 0) sop[(size_t)t * DI_] = f2bf(p);
    }
    st_out[((size_t)b * DI_ + d) * DS_ + s] = st;
}

// ---------------- gated LayerNorm -> bf16 normed ----------------
__global__ __launch_bounds__(256) void ln_kernel(
    const u16* __restrict__ so, const u16* __restrict__ z,
    const float* __restrict__ gamma, const float* __restrict__ beta,
    u16* __restrict__ normed) {
    int m = blockIdx.x;
    int tid = threadIdx.x;
    size_t base = (size_t)m * DI_;
    float v[8];
    float s = 0.f, s2 = 0.f;
#pragma unroll
    for (int j = 0; j < 8; ++j) {
        int i = tid + j * 256;
        float val = bf2f(so[base + i]) * bf2f(z[base + i]);
        v[j] = val; s += val; s2 += val * val;
    }
#pragma unroll
    for (int off = 32; off; off >>= 1) {
        s  += __shfl_xor(s,  off);
        s2 += __shfl_xor(s2, off);
    }
    __shared__ float rs[4], rq[4];
    int wave = tid >> 6;
    if ((tid & 63) == 0) { rs[wave] = s; rq[wave] = s2; }
    __syncthreads();
    s  = rs[0] + rs[1] + rs[2] + rs[3];
    s2 = rq[0] + rq[1] + rq[2] + rq[3];
    float mu  = s * (1.f / DI_);
    float var = s2 * (1.f / DI_) - mu * mu;
    float rstd = rsqrtf(var + 1e-5f);
#pragma unroll
    for (int j = 0; j < 8; ++j) {
        int i = tid + j * 256;
        float nv = (v[j] - mu) * rstd * gamma[i] + beta[i];
        normed[base + i] = f2bf(nv);
    }
}

extern "C" void kernel_launch(void* const* d_in, const int* in_sizes, int n_in,
                              void* d_out, int out_size, void* d_ws, size_t ws_size,
                              hipStream_t stream) {
    const float* x       = (const float*)d_in[0];
    const float* Win     = (const float*)d_in[1];
    const float* A_log   = (const float*)d_in[2];
    const float* WB      = (const float*)d_in[3];
    const float* WC      = (const float*)d_in[4];
    const float* Wdt     = (const float*)d_in[5];
    const float* bdt     = (const float*)d_in[6];
    const float* dt_bias = (const float*)d_in[7];
    const float* gamma   = (const float*)d_in[8];
    const float* beta    = (const float*)d_in[9];
    const float* Wout    = (const float*)d_in[10];

    float* y_out     = (float*)d_out;
    float* state_out = y_out + (size_t)B_ * T_ * D_;

    char* ws = (char*)d_ws;
    u16* xi_bf   = (u16*)(ws + 0);            // 16 MB  (4096x2048 bf16)
    u16* z_bf    = (u16*)(ws + 16777216);     // 16 MB
    u16* dt_bf   = (u16*)(ws + 33554432);     // 16 MB
    u16* so_bf   = (u16*)(ws + 50331648);     // 16 MB
    u16* nm_bf   = (u16*)(ws + 67108864);     // 16 MB
    u16* x_bf    = (u16*)(ws + 83886080);     // 8 MB
    u16* win_bf  = (u16*)(ws + 92274688);     // 8 MB
    u16* wdt_bf  = (u16*)(ws + 100663296);    // 4 MB
    u16* wout_bf = (u16*)(ws + 104857600);    // 4 MB
    float* BmB   = (float*)(ws + 109051904);  // 256 KB
    float* CmB   = (float*)(ws + 109314048);  // 256 KB

    // convert fp32 -> bf16
    {
        int n4;
        n4 = (B_ * T_ * D_) / 4;
        cvt_kernel<<<(n4 + 255) / 256, 256, 0, stream>>>(x, x_bf, n4);
        n4 = (2 * DI_ * D_) / 4;
        cvt_kernel<<<(n4 + 255) / 256, 256, 0, stream>>>(Win, win_bf, n4);
        n4 = (DI_ * D_) / 4;
        cvt_kernel<<<(n4 + 255) / 256, 256, 0, stream>>>(Wdt, wdt_bf, n4);
        n4 = (D_ * DI_) / 4;
        cvt_kernel<<<(n4 + 255) / 256, 256, 0, stream>>>(Wout, wout_bf, n4);
    }

    dim3 blk(256);
    // xi = x @ Win[0:DI]^T
    gemm_bt<EPI_BF><<<dim3(DI_ / 128, MROWS / 128), blk, 0, stream>>>(
        x_bf, win_bf, xi_bf, MROWS, DI_, D_, nullptr, nullptr);
    // z = silu(x @ Win[DI:2DI]^T)
    gemm_bt<EPI_SILU><<<dim3(DI_ / 128, MROWS / 128), blk, 0, stream>>>(
        x_bf, win_bf + (size_t)DI_ * D_, z_bf, MROWS, DI_, D_, nullptr, nullptr);
    // dt = softplus(x @ Wdt^T + bdt + dt_bias)
    gemm_bt<EPI_SP><<<dim3(DI_ / 128, MROWS / 128), blk, 0, stream>>>(
        x_bf, wdt_bf, dt_bf, MROWS, DI_, D_, bdt, dt_bias);
    // Bm, C
    bc_kernel<<<MROWS / 32, 256, 0, stream>>>(x, WB, WC, BmB, CmB);
    // sequential scan (+ final state to d_out tail)
    scan_kernel<<<(B_ * DI_) / 16, 256, 0, stream>>>(
        dt_bf, xi_bf, BmB, CmB, A_log, so_bf, state_out);
    // gated layernorm
    ln_kernel<<<MROWS, 256, 0, stream>>>(so_bf, z_bf, gamma, beta, nm_bf);
    // y = normed @ Wout^T
    gemm_bt<EPI_F32><<<dim3(D_ / 128, MROWS / 128), blk, 0, stream>>>(
        nm_bf, wout_bf, y_out, MROWS, D_, DI_, nullptr, nullptr);
}

// Round 2
// 623.454 us; speedup vs baseline: 2.0238x; 2.0238x over previous
//
#include <hip/hip_runtime.h>
#include <stdint.h>

#define B_ 2
#define T_ 2048
#define D_ 1024
#define DI_ 2048
#define DS_ 16
#define MROWS (B_*T_)
#define NC_ 16            // scan chunks
#define LCH_ (T_/NC_)     // 128 t per chunk
#define TT_ 64            // LDS sub-tile (t)

typedef unsigned short u16;
typedef __attribute__((ext_vector_type(4))) float f32x4;
typedef __attribute__((ext_vector_type(8))) short short8;
typedef __attribute__((ext_vector_type(4))) unsigned short u16x4;

__device__ __forceinline__ float bf2f(u16 u) {
    union { uint32_t i; float f; } v; v.i = ((uint32_t)u) << 16; return v.f;
}
__device__ __forceinline__ u16 f2bf(float f) {
    union { float f; uint32_t i; } v; v.f = f;
    uint32_t r = v.i + 0x7fff + ((v.i >> 16) & 1);
    return (u16)(r >> 16);
}

// ---------------- f32 -> bf16 convert (vectorized x4) ----------------
__global__ __launch_bounds__(256) void cvt_kernel(const float* __restrict__ in,
                                                  u16* __restrict__ out, int n4) {
    int i = blockIdx.x * 256 + threadIdx.x;
    if (i < n4) {
        float4 v = ((const float4*)in)[i];
        u16x4 o;
        o.x = f2bf(v.x); o.y = f2bf(v.y); o.z = f2bf(v.z); o.w = f2bf(v.w);
        ((u16x4*)out)[i] = o;
    }
}

// ---------------- bt-GEMM: out[m,n] = sum_k A[m,k] * W[n,k] ----------------
#define EPI_BF   0
#define EPI_SILU 1
#define EPI_SP   2
#define EPI_F32  3

template<int EPI>
__global__ __launch_bounds__(256) void gemm_bt(
    const u16* __restrict__ A, const u16* __restrict__ W,
    void* __restrict__ outv, int M, int N, int K,
    const float* __restrict__ b1, const float* __restrict__ b2) {
    __shared__ u16 lA[128 * 32];
    __shared__ u16 lB[128 * 32];
    const int tid  = threadIdx.x;
    const int lane = tid & 63;
    const int wave = tid >> 6;
    const int wr = wave >> 1, wc = wave & 1;
    const int m0 = blockIdx.y * 128, n0 = blockIdx.x * 128;

    f32x4 acc[4][4];
#pragma unroll
    for (int i = 0; i < 4; ++i)
#pragma unroll
        for (int j = 0; j < 4; ++j) acc[i][j] = (f32x4){0.f, 0.f, 0.f, 0.f};

    const int lrow = tid >> 2;
    const int lseg = tid & 3;

    for (int k0 = 0; k0 < K; k0 += 32) {
        __syncthreads();
#pragma unroll
        for (int it = 0; it < 2; ++it) {
            int row = it * 64 + lrow;
            const u16* sa = A + (size_t)(m0 + row) * K + k0 + lseg * 8;
            const u16* sw = W + (size_t)(n0 + row) * K + k0 + lseg * 8;
            __builtin_amdgcn_global_load_lds(
                (const __attribute__((address_space(1))) void*)sa,
                (__attribute__((address_space(3))) void*)(lA + row * 32 + lseg * 8),
                16, 0, 0);
            __builtin_amdgcn_global_load_lds(
                (const __attribute__((address_space(1))) void*)sw,
                (__attribute__((address_space(3))) void*)(lB + row * 32 + lseg * 8),
                16, 0, 0);
        }
        __syncthreads();

        const int fr = lane & 15, ks = lane >> 4;
        short8 af[4], bfr[4];
#pragma unroll
        for (int i = 0; i < 4; ++i) {
            af[i]  = *(const short8*)(lA + (wr * 64 + i * 16 + fr) * 32 + ks * 8);
            bfr[i] = *(const short8*)(lB + (wc * 64 + i * 16 + fr) * 32 + ks * 8);
        }
#pragma unroll
        for (int i = 0; i < 4; ++i)
#pragma unroll
            for (int j = 0; j < 4; ++j)
                acc[i][j] = __builtin_amdgcn_mfma_f32_16x16x32_bf16(
                    af[i], bfr[j], acc[i][j], 0, 0, 0);
    }

    const int fr = lane & 15, fq = lane >> 4;
#pragma unroll
    for (int i = 0; i < 4; ++i)
#pragma unroll
        for (int j = 0; j < 4; ++j) {
            int gn = n0 + wc * 64 + j * 16 + fr;
#pragma unroll
            for (int r = 0; r < 4; ++r) {
                int gm = m0 + wr * 64 + i * 16 + fq * 4 + r;
                float v = acc[i][j][r];
                if (EPI == EPI_SILU) v = v / (1.f + __expf(-v));
                if (EPI == EPI_SP) {
                    v += b1[gn] + b2[gn];
                    v = (v > 20.f) ? v : log1pf(__expf(v));
                }
                if (EPI == EPI_F32)
                    ((float*)outv)[(size_t)gm * N + gn] = v;
                else
                    ((u16*)outv)[(size_t)gm * N + gn] = f2bf(v);
            }
        }
}

// ---------------- Bm / C projections (N=16 each, fp32) ----------------
__global__ __launch_bounds__(256) void bc_kernel(
    const float* __restrict__ x, const float* __restrict__ WB,
    const float* __restrict__ WC, float* __restrict__ Bm, float* __restrict__ Cm) {
    __shared__ float xs[32][65];
    __shared__ float ws[32][65];
    int m0 = blockIdx.x * 32;
    int tid = threadIdx.x;
    int o = tid & 31, mg = tid >> 5;
    float acc[4] = {0.f, 0.f, 0.f, 0.f};
    for (int k0 = 0; k0 < D_; k0 += 64) {
        __syncthreads();
#pragma unroll
        for (int j = 0; j < 8; ++j) {
            int f = j * 256 + tid;
            int r = f >> 6, kk = f & 63;
            xs[r][kk] = x[(size_t)(m0 + r) * D_ + k0 + kk];
            ws[r][kk] = (r < 16) ? WB[(size_t)r * D_ + k0 + kk]
                                 : WC[(size_t)(r - 16) * D_ + k0 + kk];
        }
        __syncthreads();
#pragma unroll 8
        for (int kk = 0; kk < 64; ++kk) {
            float wv = ws[o][kk];
#pragma unroll
            for (int r = 0; r < 4; ++r)
                acc[r] = fmaf(xs[mg * 4 + r][kk], wv, acc[r]);
        }
    }
#pragma unroll
    for (int r = 0; r < 4; ++r) {
        int m = m0 + mg * 4 + r;
        if (o < 16) Bm[(size_t)m * DS_ + o] = acc[r];
        else        Cm[(size_t)m * DS_ + (o - 16)] = acc[r];
    }
}

// ============ chunked scan: pass 1 — per-chunk (P, Z) ============
// thread (s = tid&15, dl = tid>>4) handles (b, d0+dl, s); block = one chunk.
__global__ __launch_bounds__(256) void scan1_kernel(
    const u16* __restrict__ dt, const u16* __restrict__ xi,
    const float* __restrict__ Bm, const float* __restrict__ A_log,
    float* __restrict__ P, float* __restrict__ Z) {
    const int c = blockIdx.x, dblk = blockIdx.y, b = blockIdx.z;
    const int d0 = dblk * 16;
    const int tid = threadIdx.x;
    const int s = tid & 15, dl = tid >> 4;
    __shared__ u16 sdt[TT_][16];
    __shared__ u16 sxi[TT_][16];
    __shared__ float sB[TT_][16];
    float A2 = -0.5f * expf(A_log[(size_t)d0 * DS_ + tid]);
    float st = 0.f, Pp = 1.f;
    size_t tb = (size_t)b * T_;
    const int g = tid & 3, row = tid >> 2;
    for (int t0 = c * LCH_; t0 < (c + 1) * LCH_; t0 += TT_) {
        __syncthreads();
        *(u16x4*)&sdt[row][g * 4] = *(const u16x4*)(dt + (tb + t0 + row) * DI_ + d0 + g * 4);
        *(u16x4*)&sxi[row][g * 4] = *(const u16x4*)(xi + (tb + t0 + row) * DI_ + d0 + g * 4);
        *(float4*)&sB[row][g * 4] = *(const float4*)(Bm + (tb + t0 + row) * DS_ + g * 4);
        __syncthreads();
#pragma unroll 8
        for (int tt = 0; tt < TT_; ++tt) {
            float dtv = bf2f(sdt[tt][dl]);
            float xiv = bf2f(sxi[tt][dl]);
            float bv  = sB[tt][s];
            float h   = dtv * A2;
            float inv = __builtin_amdgcn_rcpf(1.f - h);
            float abar = (1.f + h) * inv;
            float u   = (dtv * inv) * (bv * xiv);
            st = fmaf(abar, st, u);
            Pp *= abar;
        }
    }
    size_t bds = ((size_t)b * DI_ + d0 + dl) * DS_ + s;
    P[bds * NC_ + c] = Pp;
    Z[bds * NC_ + c] = st;
}

// ============ pass 2 — serial combine over chunks (tiny) ============
__global__ __launch_bounds__(256) void scan2_kernel(
    const float* __restrict__ P, const float* __restrict__ Z,
    float* __restrict__ I, float* __restrict__ st_out) {
    size_t idx = (size_t)blockIdx.x * 256 + threadIdx.x;   // bds index
    const float4* p4 = (const float4*)(P + idx * NC_);
    const float4* z4 = (const float4*)(Z + idx * NC_);
    float pv[NC_], zv[NC_], iv[NC_];
#pragma unroll
    for (int q = 0; q < NC_ / 4; ++q) {
        float4 a = p4[q], bq = z4[q];
        pv[q*4+0]=a.x; pv[q*4+1]=a.y; pv[q*4+2]=a.z; pv[q*4+3]=a.w;
        zv[q*4+0]=bq.x; zv[q*4+1]=bq.y; zv[q*4+2]=bq.z; zv[q*4+3]=bq.w;
    }
    float cur = 0.f;
#pragma unroll
    for (int c = 0; c < NC_; ++c) { iv[c] = cur; cur = fmaf(pv[c], cur, zv[c]); }
    float4* i4 = (float4*)(I + idx * NC_);
#pragma unroll
    for (int q = 0; q < NC_ / 4; ++q)
        i4[q] = (float4){iv[q*4+0], iv[q*4+1], iv[q*4+2], iv[q*4+3]};
    st_out[idx] = cur;
}

// ============ pass 3 — recompute with init, emit outputs ============
__global__ __launch_bounds__(256) void scan3_kernel(
    const u16* __restrict__ dt, const u16* __restrict__ xi,
    const float* __restrict__ Bm, const float* __restrict__ Cm,
    const float* __restrict__ A_log, const float* __restrict__ I,
    u16* __restrict__ so) {
    const int c = blockIdx.x, dblk = blockIdx.y, b = blockIdx.z;
    const int d0 = dblk * 16;
    const int tid = threadIdx.x;
    const int s = tid & 15, dl = tid >> 4;
    __shared__ u16 sdt[TT_][16];
    __shared__ u16 sxi[TT_][16];
    __shared__ float sB[TT_][16];
    __shared__ float sC[TT_][16];
    __shared__ u16 so_t[TT_][16];
    float A2 = -0.5f * expf(A_log[(size_t)d0 * DS_ + tid]);
    size_t bds = ((size_t)b * DI_ + d0 + dl) * DS_ + s;
    float st = I[bds * NC_ + c];
    size_t tb = (size_t)b * T_;
    const int g = tid & 3, row = tid >> 2;
    for (int t0 = c * LCH_; t0 < (c + 1) * LCH_; t0 += TT_) {
        __syncthreads();
        *(u16x4*)&sdt[row][g * 4] = *(const u16x4*)(dt + (tb + t0 + row) * DI_ + d0 + g * 4);
        *(u16x4*)&sxi[row][g * 4] = *(const u16x4*)(xi + (tb + t0 + row) * DI_ + d0 + g * 4);
        *(float4*)&sB[row][g * 4] = *(const float4*)(Bm + (tb + t0 + row) * DS_ + g * 4);
        *(float4*)&sC[row][g * 4] = *(const float4*)(Cm + (tb + t0 + row) * DS_ + g * 4);
        __syncthreads();
#pragma unroll 4
        for (int tt = 0; tt < TT_; ++tt) {
            float dtv = bf2f(sdt[tt][dl]);
            float xiv = bf2f(sxi[tt][dl]);
            float bv  = sB[tt][s];
            float h   = dtv * A2;
            float inv = __builtin_amdgcn_rcpf(1.f - h);
            float abar = (1.f + h) * inv;
            float u   = (dtv * inv) * (bv * xiv);
            st = fmaf(abar, st, u);
            float p = st * sC[tt][s];
            p += __shfl_xor(p, 1, 16);
            p += __shfl_xor(p, 2, 16);
            p += __shfl_xor(p, 4, 16);
            p += __shfl_xor(p, 8, 16);
            if (s == 0) so_t[tt][dl] = f2bf(p);
        }
        __syncthreads();
        *(u16x4*)(so + (tb + t0 + row) * DI_ + d0 + g * 4) = *(u16x4*)&so_t[row][g * 4];
    }
}

// ---------------- gated LayerNorm -> bf16 normed ----------------
__global__ __launch_bounds__(256) void ln_kernel(
    const u16* __restrict__ so, const u16* __restrict__ z,
    const float* __restrict__ gamma, const float* __restrict__ beta,
    u16* __restrict__ normed) {
    int m = blockIdx.x;
    int tid = threadIdx.x;
    size_t base = (size_t)m * DI_;
    float v[8];
    float s = 0.f, s2 = 0.f;
#pragma unroll
    for (int j = 0; j < 8; ++j) {
        int i = tid + j * 256;
        float val = bf2f(so[base + i]) * bf2f(z[base + i]);
        v[j] = val; s += val; s2 += val * val;
    }
#pragma unroll
    for (int off = 32; off; off >>= 1) {
        s  += __shfl_xor(s,  off);
        s2 += __shfl_xor(s2, off);
    }
    __shared__ float rs[4], rq[4];
    int wave = tid >> 6;
    if ((tid & 63) == 0) { rs[wave] = s; rq[wave] = s2; }
    __syncthreads();
    s  = rs[0] + rs[1] + rs[2] + rs[3];
    s2 = rq[0] + rq[1] + rq[2] + rq[3];
    float mu  = s * (1.f / DI_);
    float var = s2 * (1.f / DI_) - mu * mu;
    float rstd = rsqrtf(var + 1e-5f);
#pragma unroll
    for (int j = 0; j < 8; ++j) {
        int i = tid + j * 256;
        float nv = (v[j] - mu) * rstd * gamma[i] + beta[i];
        normed[base + i] = f2bf(nv);
    }
}

extern "C" void kernel_launch(void* const* d_in, const int* in_sizes, int n_in,
                              void* d_out, int out_size, void* d_ws, size_t ws_size,
                              hipStream_t stream) {
    const float* x       = (const float*)d_in[0];
    const float* Win     = (const float*)d_in[1];
    const float* A_log   = (const float*)d_in[2];
    const float* WB      = (const float*)d_in[3];
    const float* WC      = (const float*)d_in[4];
    const float* Wdt     = (const float*)d_in[5];
    const float* bdt     = (const float*)d_in[6];
    const float* dt_bias = (const float*)d_in[7];
    const float* gamma   = (const float*)d_in[8];
    const float* beta    = (const float*)d_in[9];
    const float* Wout    = (const float*)d_in[10];

    float* y_out     = (float*)d_out;
    float* state_out = y_out + (size_t)B_ * T_ * D_;

    char* ws = (char*)d_ws;
    u16* xi_bf   = (u16*)(ws + 0);            // 16 MB
    u16* z_bf    = (u16*)(ws + 16777216);     // 16 MB
    u16* dt_bf   = (u16*)(ws + 33554432);     // 16 MB
    u16* so_bf   = (u16*)(ws + 50331648);     // 16 MB
    u16* nm_bf   = (u16*)(ws + 67108864);     // 16 MB
    u16* x_bf    = (u16*)(ws + 83886080);     // 8 MB  (dead after GEMMs -> reused as P)
    u16* win_bf  = (u16*)(ws + 92274688);     // 8 MB  (dead after GEMMs -> reused as Z, I)
    u16* wdt_bf  = (u16*)(ws + 100663296);    // 4 MB
    u16* wout_bf = (u16*)(ws + 104857600);    // 4 MB  (needed by final GEMM - not reused)
    float* BmB   = (float*)(ws + 109051904);  // 256 KB
    float* CmB   = (float*)(ws + 109314048);  // 256 KB

    // P/Z/I (4 MB each, NC_=16) alias x_bf / win_bf which are dead after the GEMMs
    float* Pc = (float*)(ws + 83886080);      // 4 MB
    float* Zc = (float*)(ws + 92274688);      // 4 MB
    float* Ic = (float*)(ws + 96468992);      // 4 MB

    {
        int n4;
        n4 = (B_ * T_ * D_) / 4;
        cvt_kernel<<<(n4 + 255) / 256, 256, 0, stream>>>(x, x_bf, n4);
        n4 = (2 * DI_ * D_) / 4;
        cvt_kernel<<<(n4 + 255) / 256, 256, 0, stream>>>(Win, win_bf, n4);
        n4 = (DI_ * D_) / 4;
        cvt_kernel<<<(n4 + 255) / 256, 256, 0, stream>>>(Wdt, wdt_bf, n4);
        n4 = (D_ * DI_) / 4;
        cvt_kernel<<<(n4 + 255) / 256, 256, 0, stream>>>(Wout, wout_bf, n4);
    }

    dim3 blk(256);
    gemm_bt<EPI_BF><<<dim3(DI_ / 128, MROWS / 128), blk, 0, stream>>>(
        x_bf, win_bf, xi_bf, MROWS, DI_, D_, nullptr, nullptr);
    gemm_bt<EPI_SILU><<<dim3(DI_ / 128, MROWS / 128), blk, 0, stream>>>(
        x_bf, win_bf + (size_t)DI_ * D_, z_bf, MROWS, DI_, D_, nullptr, nullptr);
    gemm_bt<EPI_SP><<<dim3(DI_ / 128, MROWS / 128), blk, 0, stream>>>(
        x_bf, wdt_bf, dt_bf, MROWS, DI_, D_, bdt, dt_bias);
    bc_kernel<<<MROWS / 32, 256, 0, stream>>>(x, WB, WC, BmB, CmB);

    // chunked scan (3 passes) — x_bf/win_bf are dead from here on
    scan1_kernel<<<dim3(NC_, DI_ / 16, B_), blk, 0, stream>>>(
        dt_bf, xi_bf, BmB, A_log, Pc, Zc);
    scan2_kernel<<<(B_ * DI_ * DS_) / 256, blk, 0, stream>>>(
        Pc, Zc, Ic, state_out);
    scan3_kernel<<<dim3(NC_, DI_ / 16, B_), blk, 0, stream>>>(
        dt_bf, xi_bf, BmB, CmB, A_log, Ic, so_bf);

    ln_kernel<<<MROWS, 256, 0, stream>>>(so_bf, z_bf, gamma, beta, nm_bf);
    gemm_bt<EPI_F32><<<dim3(D_ / 128, MROWS / 128), blk, 0, stream>>>(
        nm_bf, wout_bf, y_out, MROWS, D_, DI_, nullptr, nullptr);
}

// Round 6
// 443.149 us; speedup vs baseline: 2.8472x; 1.4069x over previous
//
#include <hip/hip_runtime.h>
#include <stdint.h>

#define B_ 2
#define T_ 2048
#define D_ 1024
#define DI_ 2048
#define DS_ 16
#define MROWS (B_*T_)
#define NC_ 32            // scan chunks
#define CL_ (T_/NC_)      // 64 t per chunk
#define TT_ 32            // LDS tile (t)

typedef unsigned short u16;
typedef __attribute__((ext_vector_type(4))) float f32x4;
typedef __attribute__((ext_vector_type(8))) short short8;
typedef __attribute__((ext_vector_type(4))) unsigned short u16x4;

__device__ __forceinline__ float bf2f(u16 u) {
    union { uint32_t i; float f; } v; v.i = ((uint32_t)u) << 16; return v.f;
}
__device__ __forceinline__ u16 f2bf(float f) {
    union { float f; uint32_t i; } v; v.f = f;
    uint32_t r = v.i + 0x7fff + ((v.i >> 16) & 1);
    return (u16)(r >> 16);
}

// ---------------- f32 -> bf16 convert (vectorized x4) ----------------
__global__ __launch_bounds__(256) void cvt_kernel(const float* __restrict__ in,
                                                  u16* __restrict__ out, int n4) {
    int i = blockIdx.x * 256 + threadIdx.x;
    if (i < n4) {
        float4 v = ((const float4*)in)[i];
        u16x4 o;
        o.x = f2bf(v.x); o.y = f2bf(v.y); o.z = f2bf(v.z); o.w = f2bf(v.w);
        ((u16x4*)out)[i] = o;
    }
}

// ============ fused input GEMM: [xi | z | dt] = x @ [Win; Wdt]^T ============
// M=4096, K=1024, fused N=6144. Region per 2048-col band (block-uniform).
__global__ __launch_bounds__(256) void gemm_in(
    const u16* __restrict__ A, const u16* __restrict__ Win,
    const u16* __restrict__ Wdt,
    u16* __restrict__ xi, u16* __restrict__ z, u16* __restrict__ dtout,
    const float* __restrict__ b1, const float* __restrict__ b2) {
    __shared__ u16 lA[128 * 32];
    __shared__ u16 lB[128 * 32];
    const int K = D_;
    const int tid  = threadIdx.x;
    const int lane = tid & 63;
    const int wave = tid >> 6;
    const int wr = wave >> 1, wc = wave & 1;
    const int m0 = blockIdx.y * 128, n0 = blockIdx.x * 128;
    const int region = n0 >> 11;   // 0:xi 1:z 2:dt
    const u16* W = (region < 2) ? (Win + (size_t)n0 * K)
                                : (Wdt + (size_t)(n0 - 4096) * K);

    f32x4 acc[4][4];
#pragma unroll
    for (int i = 0; i < 4; ++i)
#pragma unroll
        for (int j = 0; j < 4; ++j) acc[i][j] = (f32x4){0.f, 0.f, 0.f, 0.f};

    const int lrow = tid >> 2;
    const int lseg = tid & 3;

    for (int k0 = 0; k0 < K; k0 += 32) {
        __syncthreads();
#pragma unroll
        for (int it = 0; it < 2; ++it) {
            int row = it * 64 + lrow;
            const u16* sa = A + (size_t)(m0 + row) * K + k0 + lseg * 8;
            const u16* sw = W + (size_t)row * K + k0 + lseg * 8;
            __builtin_amdgcn_global_load_lds(
                (const __attribute__((address_space(1))) void*)sa,
                (__attribute__((address_space(3))) void*)(lA + row * 32 + lseg * 8),
                16, 0, 0);
            __builtin_amdgcn_global_load_lds(
                (const __attribute__((address_space(1))) void*)sw,
                (__attribute__((address_space(3))) void*)(lB + row * 32 + lseg * 8),
                16, 0, 0);
        }
        __syncthreads();

        const int fr = lane & 15, ks = lane >> 4;
        short8 af[4], bfr[4];
#pragma unroll
        for (int i = 0; i < 4; ++i) {
            af[i]  = *(const short8*)(lA + (wr * 64 + i * 16 + fr) * 32 + ks * 8);
            bfr[i] = *(const short8*)(lB + (wc * 64 + i * 16 + fr) * 32 + ks * 8);
        }
#pragma unroll
        for (int i = 0; i < 4; ++i)
#pragma unroll
            for (int j = 0; j < 4; ++j)
                acc[i][j] = __builtin_amdgcn_mfma_f32_16x16x32_bf16(
                    af[i], bfr[j], acc[i][j], 0, 0, 0);
    }

    const int fr = lane & 15, fq = lane >> 4;
#pragma unroll
    for (int i = 0; i < 4; ++i)
#pragma unroll
        for (int j = 0; j < 4; ++j) {
            int gnl = n0 + wc * 64 + j * 16 + fr;
#pragma unroll
            for (int r = 0; r < 4; ++r) {
                int gm = m0 + wr * 64 + i * 16 + fq * 4 + r;
                float v = acc[i][j][r];
                if (region == 0) {
                    xi[(size_t)gm * DI_ + gnl] = f2bf(v);
                } else if (region == 1) {
                    v = v / (1.f + __expf(-v));
                    z[(size_t)gm * DI_ + (gnl - 2048)] = f2bf(v);
                } else {
                    int gn = gnl - 4096;
                    v += b1[gn] + b2[gn];
                    v = (v > 20.f) ? v : log1pf(__expf(v));
                    dtout[(size_t)gm * DI_ + gn] = f2bf(v);
                }
            }
        }
}

// ---------------- out GEMM: y = normed @ Wout^T (f32 out) ----------------
__global__ __launch_bounds__(256) void gemm_out(
    const u16* __restrict__ A, const u16* __restrict__ W,
    float* __restrict__ out, int M, int N, int K) {
    __shared__ u16 lA[128 * 32];
    __shared__ u16 lB[128 * 32];
    const int tid  = threadIdx.x;
    const int lane = tid & 63;
    const int wave = tid >> 6;
    const int wr = wave >> 1, wc = wave & 1;
    const int m0 = blockIdx.y * 128, n0 = blockIdx.x * 128;

    f32x4 acc[4][4];
#pragma unroll
    for (int i = 0; i < 4; ++i)
#pragma unroll
        for (int j = 0; j < 4; ++j) acc[i][j] = (f32x4){0.f, 0.f, 0.f, 0.f};

    const int lrow = tid >> 2;
    const int lseg = tid & 3;

    for (int k0 = 0; k0 < K; k0 += 32) {
        __syncthreads();
#pragma unroll
        for (int it = 0; it < 2; ++it) {
            int row = it * 64 + lrow;
            const u16* sa = A + (size_t)(m0 + row) * K + k0 + lseg * 8;
            const u16* sw = W + (size_t)(n0 + row) * K + k0 + lseg * 8;
            __builtin_amdgcn_global_load_lds(
                (const __attribute__((address_space(1))) void*)sa,
                (__attribute__((address_space(3))) void*)(lA + row * 32 + lseg * 8),
                16, 0, 0);
            __builtin_amdgcn_global_load_lds(
                (const __attribute__((address_space(1))) void*)sw,
                (__attribute__((address_space(3))) void*)(lB + row * 32 + lseg * 8),
                16, 0, 0);
        }
        __syncthreads();

        const int fr = lane & 15, ks = lane >> 4;
        short8 af[4], bfr[4];
#pragma unroll
        for (int i = 0; i < 4; ++i) {
            af[i]  = *(const short8*)(lA + (wr * 64 + i * 16 + fr) * 32 + ks * 8);
            bfr[i] = *(const short8*)(lB + (wc * 64 + i * 16 + fr) * 32 + ks * 8);
        }
#pragma unroll
        for (int i = 0; i < 4; ++i)
#pragma unroll
            for (int j = 0; j < 4; ++j)
                acc[i][j] = __builtin_amdgcn_mfma_f32_16x16x32_bf16(
                    af[i], bfr[j], acc[i][j], 0, 0, 0);
    }

    const int fr = lane & 15, fq = lane >> 4;
#pragma unroll
    for (int i = 0; i < 4; ++i)
#pragma unroll
        for (int j = 0; j < 4; ++j) {
            int gn = n0 + wc * 64 + j * 16 + fr;
#pragma unroll
            for (int r = 0; r < 4; ++r) {
                int gm = m0 + wr * 64 + i * 16 + fq * 4 + r;
                out[(size_t)gm * N + gn] = acc[i][j][r];
            }
        }
}

// ---------------- Bm / C projections (N=16 each, fp32) ----------------
__global__ __launch_bounds__(256) void bc_kernel(
    const float* __restrict__ x, const float* __restrict__ WB,
    const float* __restrict__ WC, float* __restrict__ Bm, float* __restrict__ Cm) {
    __shared__ float xs[32][65];
    __shared__ float ws[32][65];
    int m0 = blockIdx.x * 32;
    int tid = threadIdx.x;
    int o = tid & 31, mg = tid >> 5;
    float acc[4] = {0.f, 0.f, 0.f, 0.f};
    for (int k0 = 0; k0 < D_; k0 += 64) {
        __syncthreads();
#pragma unroll
        for (int j = 0; j < 8; ++j) {
            int f = j * 256 + tid;
            int r = f >> 6, kk = f & 63;
            xs[r][kk] = x[(size_t)(m0 + r) * D_ + k0 + kk];
            ws[r][kk] = (r < 16) ? WB[(size_t)r * D_ + k0 + kk]
                                 : WC[(size_t)(r - 16) * D_ + k0 + kk];
        }
        __syncthreads();
#pragma unroll 8
        for (int kk = 0; kk < 64; ++kk) {
            float wv = ws[o][kk];
#pragma unroll
            for (int r = 0; r < 4; ++r)
                acc[r] = fmaf(xs[mg * 4 + r][kk], wv, acc[r]);
        }
    }
#pragma unroll
    for (int r = 0; r < 4; ++r) {
        int m = m0 + mg * 4 + r;
        if (o < 16) Bm[(size_t)m * DS_ + o] = acc[r];
        else        Cm[(size_t)m * DS_ + (o - 16)] = acc[r];
    }
}

// ============ chunked scan, thread-owns-d layout ============
// Thread owns (b, d), holds 16 s-states in registers. Block = 256 d's.
// grid = (NC_, DI_/256, B_).

// pass 1 — per-chunk decay products P[s] and zero-input responses Z[s]
__global__ __launch_bounds__(256) void scan1_kernel(
    const u16* __restrict__ dt, const u16* __restrict__ xi,
    const float* __restrict__ Bm, const float* __restrict__ A_log,
    float* __restrict__ P, float* __restrict__ Z) {
    const int c = blockIdx.x, dblk = blockIdx.y, b = blockIdx.z;
    const int tid = threadIdx.x;
    const int d = dblk * 256 + tid;
    __shared__ u16 sdt[TT_ * 256];
    __shared__ u16 sxi[TT_ * 256];
    __shared__ float sB[TT_ * 16];
    float A2[16], st[16], Pp[16];
#pragma unroll
    for (int s = 0; s < 16; ++s) {
        A2[s] = -0.5f * __expf(A_log[(size_t)d * DS_ + s]);
        st[s] = 0.f; Pp[s] = 1.f;
    }
    const size_t tb = (size_t)b * T_;
    for (int t0 = c * CL_; t0 < (c + 1) * CL_; t0 += TT_) {
        __syncthreads();
#pragma unroll
        for (int r = 0; r < 4; ++r) {
            int flat = r * 2048 + tid * 8;
            int row = flat >> 8, col = flat & 255;
            const u16* s1 = dt + (tb + t0 + row) * DI_ + dblk * 256 + col;
            const u16* s2 = xi + (tb + t0 + row) * DI_ + dblk * 256 + col;
            __builtin_amdgcn_global_load_lds(
                (const __attribute__((address_space(1))) void*)s1,
                (__attribute__((address_space(3))) void*)(sdt + flat), 16, 0, 0);
            __builtin_amdgcn_global_load_lds(
                (const __attribute__((address_space(1))) void*)s2,
                (__attribute__((address_space(3))) void*)(sxi + flat), 16, 0, 0);
        }
        *(float2*)(sB + tid * 2) = *(const float2*)(Bm + (tb + t0) * DS_ + tid * 2);
        __syncthreads();
#pragma unroll 2
        for (int tt = 0; tt < TT_; ++tt) {
            float dtv = bf2f(sdt[tt * 256 + tid]);
            float xiv = bf2f(sxi[tt * 256 + tid]);
            float dxv = dtv * xiv;
            float bv[16];
            *(float4*)&bv[0]  = *(const float4*)(sB + tt * 16);
            *(float4*)&bv[4]  = *(const float4*)(sB + tt * 16 + 4);
            *(float4*)&bv[8]  = *(const float4*)(sB + tt * 16 + 8);
            *(float4*)&bv[12] = *(const float4*)(sB + tt * 16 + 12);
#pragma unroll
            for (int s = 0; s < 16; ++s) {
                float a2   = fmaf(dtv, -A2[s], 1.f);
                float inv  = __builtin_amdgcn_rcpf(a2);
                float abar = fmaf(2.f, inv, -1.f);
                st[s] = fmaf(abar, st[s], (inv * bv[s]) * dxv);
                Pp[s] *= abar;
            }
        }
    }
    size_t base = (((size_t)b * DI_ + d) * NC_ + c) * 16;
#pragma unroll
    for (int q = 0; q < 4; ++q) {
        *(float4*)(P + base + q * 4) = (float4){Pp[q*4], Pp[q*4+1], Pp[q*4+2], Pp[q*4+3]};
        *(float4*)(Z + base + q * 4) = (float4){st[q*4], st[q*4+1], st[q*4+2], st[q*4+3]};
    }
}

// pass 2 — serial combine over chunks; writes chunk-init states I in-place into P
__global__ __launch_bounds__(256) void scan2_kernel(
    float* __restrict__ P, const float* __restrict__ Z,
    float* __restrict__ st_out) {
    size_t idx = (size_t)blockIdx.x * 256 + threadIdx.x;   // (b*DI+d)*16+s
    size_t bd = idx >> 4;
    int s = (int)(idx & 15);
    float cur = 0.f;
    for (int c = 0; c < NC_; ++c) {
        size_t a = (bd * NC_ + c) * 16 + s;
        float p = P[a], zv = Z[a];
        P[a] = cur;                       // I: state at chunk start
        cur = fmaf(p, cur, zv);
    }
    st_out[idx] = cur;
}

// pass 3 — recompute with init states, emit dot-product outputs
__global__ __launch_bounds__(256) void scan3_kernel(
    const u16* __restrict__ dt, const u16* __restrict__ xi,
    const float* __restrict__ Bm, const float* __restrict__ Cm,
    const float* __restrict__ A_log, const float* __restrict__ I,
    u16* __restrict__ so) {
    const int c = blockIdx.x, dblk = blockIdx.y, b = blockIdx.z;
    const int tid = threadIdx.x;
    const int d = dblk * 256 + tid;
    __shared__ u16 sdt[TT_ * 256];
    __shared__ u16 sxi[TT_ * 256];
    __shared__ float sB[TT_ * 16];
    __shared__ float sC[TT_ * 16];
    float A2[16], st[16];
#pragma unroll
    for (int s = 0; s < 16; ++s)
        A2[s] = -0.5f * __expf(A_log[(size_t)d * DS_ + s]);
    size_t base = (((size_t)b * DI_ + d) * NC_ + c) * 16;
#pragma unroll
    for (int q = 0; q < 4; ++q) {
        float4 v = *(const float4*)(I + base + q * 4);
        st[q*4] = v.x; st[q*4+1] = v.y; st[q*4+2] = v.z; st[q*4+3] = v.w;
    }
    const size_t tb = (size_t)b * T_;
    for (int t0 = c * CL_; t0 < (c + 1) * CL_; t0 += TT_) {
        __syncthreads();
#pragma unroll
        for (int r = 0; r < 4; ++r) {
            int flat = r * 2048 + tid * 8;
            int row = flat >> 8, col = flat & 255;
            const u16* s1 = dt + (tb + t0 + row) * DI_ + dblk * 256 + col;
            const u16* s2 = xi + (tb + t0 + row) * DI_ + dblk * 256 + col;
            __builtin_amdgcn_global_load_lds(
                (const __attribute__((address_space(1))) void*)s1,
                (__attribute__((address_space(3))) void*)(sdt + flat), 16, 0, 0);
            __builtin_amdgcn_global_load_lds(
                (const __attribute__((address_space(1))) void*)s2,
                (__attribute__((address_space(3))) void*)(sxi + flat), 16, 0, 0);
        }
        *(float2*)(sB + tid * 2) = *(const float2*)(Bm + (tb + t0) * DS_ + tid * 2);
        *(float2*)(sC + tid * 2) = *(const float2*)(Cm + (tb + t0) * DS_ + tid * 2);
        __syncthreads();
#pragma unroll 2
        for (int tt = 0; tt < TT_; ++tt) {
            float dtv = bf2f(sdt[tt * 256 + tid]);
            float xiv = bf2f(sxi[tt * 256 + tid]);
            float dxv = dtv * xiv;
            float bv[16], cv[16];
            *(float4*)&bv[0]  = *(const float4*)(sB + tt * 16);
            *(float4*)&bv[4]  = *(const float4*)(sB + tt * 16 + 4);
            *(float4*)&bv[8]  = *(const float4*)(sB + tt * 16 + 8);
            *(float4*)&bv[12] = *(const float4*)(sB + tt * 16 + 12);
            *(float4*)&cv[0]  = *(const float4*)(sC + tt * 16);
            *(float4*)&cv[4]  = *(const float4*)(sC + tt * 16 + 4);
            *(float4*)&cv[8]  = *(const float4*)(sC + tt * 16 + 8);
            *(float4*)&cv[12] = *(const float4*)(sC + tt * 16 + 12);
            float acc = 0.f;
#pragma unroll
            for (int s = 0; s < 16; ++s) {
                float a2   = fmaf(dtv, -A2[s], 1.f);
                float inv  = __builtin_amdgcn_rcpf(a2);
                float abar = fmaf(2.f, inv, -1.f);
                st[s] = fmaf(abar, st[s], (inv * bv[s]) * dxv);
                acc = fmaf(st[s], cv[s], acc);
            }
            so[(tb + t0 + tt) * DI_ + d] = f2bf(acc);
        }
    }
}

// ---------------- gated LayerNorm -> bf16 normed ----------------
__global__ __launch_bounds__(256) void ln_kernel(
    const u16* __restrict__ so, const u16* __restrict__ z,
    const float* __restrict__ gamma, const float* __restrict__ beta,
    u16* __restrict__ normed) {
    int m = blockIdx.x;
    int tid = threadIdx.x;
    size_t base = (size_t)m * DI_;
    float v[8];
    float s = 0.f, s2 = 0.f;
#pragma unroll
    for (int j = 0; j < 8; ++j) {
        int i = tid + j * 256;
        float val = bf2f(so[base + i]) * bf2f(z[base + i]);
        v[j] = val; s += val; s2 += val * val;
    }
#pragma unroll
    for (int off = 32; off; off >>= 1) {
        s  += __shfl_xor(s,  off);
        s2 += __shfl_xor(s2, off);
    }
    __shared__ float rs[4], rq[4];
    int wave = tid >> 6;
    if ((tid & 63) == 0) { rs[wave] = s; rq[wave] = s2; }
    __syncthreads();
    s  = rs[0] + rs[1] + rs[2] + rs[3];
    s2 = rq[0] + rq[1] + rq[2] + rq[3];
    float mu  = s * (1.f / DI_);
    float var = s2 * (1.f / DI_) - mu * mu;
    float rstd = rsqrtf(var + 1e-5f);
#pragma unroll
    for (int j = 0; j < 8; ++j) {
        int i = tid + j * 256;
        float nv = (v[j] - mu) * rstd * gamma[i] + beta[i];
        normed[base + i] = f2bf(nv);
    }
}

extern "C" void kernel_launch(void* const* d_in, const int* in_sizes, int n_in,
                              void* d_out, int out_size, void* d_ws, size_t ws_size,
                              hipStream_t stream) {
    const float* x       = (const float*)d_in[0];
    const float* Win     = (const float*)d_in[1];
    const float* A_log   = (const float*)d_in[2];
    const float* WB      = (const float*)d_in[3];
    const float* WC      = (const float*)d_in[4];
    const float* Wdt     = (const float*)d_in[5];
    const float* bdt     = (const float*)d_in[6];
    const float* dt_bias = (const float*)d_in[7];
    const float* gamma   = (const float*)d_in[8];
    const float* beta    = (const float*)d_in[9];
    const float* Wout    = (const float*)d_in[10];

    float* y_out     = (float*)d_out;
    float* state_out = y_out + (size_t)B_ * T_ * D_;

    char* ws = (char*)d_ws;
    u16* xi_bf   = (u16*)(ws + 0);            // 16 MB
    u16* z_bf    = (u16*)(ws + 16777216);     // 16 MB
    u16* dt_bf   = (u16*)(ws + 33554432);     // 16 MB
    u16* so_bf   = (u16*)(ws + 50331648);     // 16 MB
    u16* nm_bf   = (u16*)(ws + 67108864);     // 16 MB
    u16* x_bf    = (u16*)(ws + 83886080);     // 8 MB  (dead after GEMMs -> P/I)
    u16* win_bf  = (u16*)(ws + 92274688);     // 8 MB  (dead after GEMMs -> Z)
    u16* wdt_bf  = (u16*)(ws + 100663296);    // 4 MB
    u16* wout_bf = (u16*)(ws + 104857600);    // 4 MB
    float* BmB   = (float*)(ws + 109051904);  // 256 KB
    float* CmB   = (float*)(ws + 109314048);  // 256 KB

    // P (8 MB, becomes I in-place) and Z (8 MB) alias dead x_bf / win_bf
    float* Pc = (float*)(ws + 83886080);
    float* Zc = (float*)(ws + 92274688);

    {
        int n4;
        n4 = (B_ * T_ * D_) / 4;
        cvt_kernel<<<(n4 + 255) / 256, 256, 0, stream>>>(x, x_bf, n4);
        n4 = (2 * DI_ * D_) / 4;
        cvt_kernel<<<(n4 + 255) / 256, 256, 0, stream>>>(Win, win_bf, n4);
        n4 = (DI_ * D_) / 4;
        cvt_kernel<<<(n4 + 255) / 256, 256, 0, stream>>>(Wdt, wdt_bf, n4);
        n4 = (D_ * DI_) / 4;
        cvt_kernel<<<(n4 + 255) / 256, 256, 0, stream>>>(Wout, wout_bf, n4);
    }

    dim3 blk(256);
    // fused [xi | z | dt]
    gemm_in<<<dim3(6144 / 128, MROWS / 128), blk, 0, stream>>>(
        x_bf, win_bf, wdt_bf, xi_bf, z_bf, dt_bf, bdt, dt_bias);
    bc_kernel<<<MROWS / 32, 256, 0, stream>>>(x, WB, WC, BmB, CmB);

    // chunked scan (3 passes) — x_bf/win_bf dead from here
    scan1_kernel<<<dim3(NC_, DI_ / 256, B_), blk, 0, stream>>>(
        dt_bf, xi_bf, BmB, A_log, Pc, Zc);
    scan2_kernel<<<(B_ * DI_ * DS_) / 256, blk, 0, stream>>>(
        Pc, Zc, state_out);
    scan3_kernel<<<dim3(NC_, DI_ / 256, B_), blk, 0, stream>>>(
        dt_bf, xi_bf, BmB, CmB, A_log, Pc, so_bf);

    ln_kernel<<<MROWS, 256, 0, stream>>>(so_bf, z_bf, gamma, beta, nm_bf);
    gemm_out<<<dim3(D_ / 128, MROWS / 128), blk, 0, stream>>>(
        nm_bf, wout_bf, y_out, MROWS, D_, DI_);
}

// Round 7
// 415.582 us; speedup vs baseline: 3.0361x; 1.0663x over previous
//
#include <hip/hip_runtime.h>
#include <stdint.h>

#define B_ 2
#define T_ 2048
#define D_ 1024
#define DI_ 2048
#define DS_ 16
#define MROWS (B_*T_)
#define NC_ 32            // scan chunks
#define CL_ (T_/NC_)      // 64 t per chunk
#define TT_ 32            // LDS tile (t)

typedef unsigned short u16;
typedef __attribute__((ext_vector_type(4))) float f32x4;
typedef __attribute__((ext_vector_type(8))) short short8;
typedef __attribute__((ext_vector_type(4))) unsigned short u16x4;

__device__ __forceinline__ float bf2f(u16 u) {
    union { uint32_t i; float f; } v; v.i = ((uint32_t)u) << 16; return v.f;
}
__device__ __forceinline__ u16 f2bf(float f) {
    union { float f; uint32_t i; } v; v.f = f;
    uint32_t r = v.i + 0x7fff + ((v.i >> 16) & 1);
    return (u16)(r >> 16);
}

// ---------------- f32 -> bf16 convert (vectorized x4) ----------------
__global__ __launch_bounds__(256) void cvt_kernel(const float* __restrict__ in,
                                                  u16* __restrict__ out, int n4) {
    int i = blockIdx.x * 256 + threadIdx.x;
    if (i < n4) {
        float4 v = ((const float4*)in)[i];
        u16x4 o;
        o.x = f2bf(v.x); o.y = f2bf(v.y); o.z = f2bf(v.z); o.w = f2bf(v.w);
        ((u16x4*)out)[i] = o;
    }
}

// ============ fused input GEMM: [xi | z | dt] = x @ [Win; Wdt]^T ============
// M=4096, K=1024, fused N=6144. 128x128 tile, BK=32, double-buffered LDS with
// prefetch-ahead staging (1 barrier/K-step), XOR seg-swizzle (2-way banks),
// XCD-aware block swizzle.
__global__ __launch_bounds__(256) void gemm_in(
    const u16* __restrict__ A, const u16* __restrict__ Win,
    const u16* __restrict__ Wdt,
    u16* __restrict__ xi, u16* __restrict__ z, u16* __restrict__ dtout,
    const float* __restrict__ b1, const float* __restrict__ b2) {
    __shared__ u16 lA[2][128 * 32];
    __shared__ u16 lB[2][128 * 32];
    const int K = D_;
    const int tid  = threadIdx.x;
    const int lane = tid & 63;
    const int wave = tid >> 6;
    const int wr = wave >> 1, wc = wave & 1;

    // XCD-aware swizzle (nwg = 48*32 = 1536, %8==0 -> bijective)
    const int nwg = gridDim.x * gridDim.y;
    const int lin = blockIdx.y * gridDim.x + blockIdx.x;
    const int swz = (lin & 7) * (nwg >> 3) + (lin >> 3);
    const int bx = swz % gridDim.x, by = swz / gridDim.x;
    const int m0 = by * 128, n0 = bx * 128;
    const int region = n0 >> 11;   // 0:xi 1:z 2:dt
    const u16* W = (region < 2) ? (Win + (size_t)n0 * K)
                                : (Wdt + (size_t)(n0 - 4096) * K);

    f32x4 acc[4][4];
#pragma unroll
    for (int i = 0; i < 4; ++i)
#pragma unroll
        for (int j = 0; j < 4; ++j) acc[i][j] = (f32x4){0.f, 0.f, 0.f, 0.f};

    // staging: thread -> (row = tid>>2, linear seg' = tid&3); the global
    // k-segment fetched is seg' ^ ((row>>1)&3)  [involution swizzle]
    const int srow = tid >> 2;
    const int sseg = tid & 3;
    const int gseg = sseg ^ ((srow >> 1) & 3);

    // fragment read: row r, want k-seg ks -> read LDS seg (ks ^ ((r>>1)&3));
    // (r>>1)&3 reduces to (fr>>1)&3 since r = base16 + fr with base16 % 16 == 0
    const int fr = lane & 15, ks = lane >> 4;
    const int rsw = ks ^ ((fr >> 1) & 3);

    auto STAGE = [&](int buf, int k0) {
#pragma unroll
        for (int it = 0; it < 2; ++it) {
            int row = it * 64 + srow;
            const u16* sa = A + (size_t)(m0 + row) * K + k0 + gseg * 8;
            const u16* sw = W + (size_t)row * K + k0 + gseg * 8;
            __builtin_amdgcn_global_load_lds(
                (const __attribute__((address_space(1))) void*)sa,
                (__attribute__((address_space(3))) void*)(&lA[buf][row * 32 + sseg * 8]),
                16, 0, 0);
            __builtin_amdgcn_global_load_lds(
                (const __attribute__((address_space(1))) void*)sw,
                (__attribute__((address_space(3))) void*)(&lB[buf][row * 32 + sseg * 8]),
                16, 0, 0);
        }
    };

    STAGE(0, 0);
    __syncthreads();
    int cur = 0;
    for (int k0 = 0; k0 < K; k0 += 32) {
        if (k0 + 32 < K) STAGE(cur ^ 1, k0 + 32);   // prefetch overlaps compute
        short8 af[4], bfr[4];
#pragma unroll
        for (int i = 0; i < 4; ++i) {
            af[i]  = *(const short8*)(&lA[cur][(wr * 64 + i * 16 + fr) * 32 + rsw * 8]);
            bfr[i] = *(const short8*)(&lB[cur][(wc * 64 + i * 16 + fr) * 32 + rsw * 8]);
        }
#pragma unroll
        for (int i = 0; i < 4; ++i)
#pragma unroll
            for (int j = 0; j < 4; ++j)
                acc[i][j] = __builtin_amdgcn_mfma_f32_16x16x32_bf16(
                    af[i], bfr[j], acc[i][j], 0, 0, 0);
        __syncthreads();   // drains vmcnt (prefetch) + lgkm; 1 barrier/K-step
        cur ^= 1;
    }

    const int fq = lane >> 4;
#pragma unroll
    for (int i = 0; i < 4; ++i)
#pragma unroll
        for (int j = 0; j < 4; ++j) {
            int gnl = n0 + wc * 64 + j * 16 + fr;
#pragma unroll
            for (int r = 0; r < 4; ++r) {
                int gm = m0 + wr * 64 + i * 16 + fq * 4 + r;
                float v = acc[i][j][r];
                if (region == 0) {
                    xi[(size_t)gm * DI_ + gnl] = f2bf(v);
                } else if (region == 1) {
                    v = v / (1.f + __expf(-v));
                    z[(size_t)gm * DI_ + (gnl - 2048)] = f2bf(v);
                } else {
                    int gn = gnl - 4096;
                    v += b1[gn] + b2[gn];
                    v = (v > 20.f) ? v : log1pf(__expf(v));
                    dtout[(size_t)gm * DI_ + gn] = f2bf(v);
                }
            }
        }
}

// ---------------- out GEMM: y = normed @ Wout^T (f32 out) ----------------
__global__ __launch_bounds__(256) void gemm_out(
    const u16* __restrict__ A, const u16* __restrict__ W,
    float* __restrict__ out, int M, int N, int K) {
    __shared__ u16 lA[2][128 * 32];
    __shared__ u16 lB[2][128 * 32];
    const int tid  = threadIdx.x;
    const int lane = tid & 63;
    const int wave = tid >> 6;
    const int wr = wave >> 1, wc = wave & 1;

    const int nwg = gridDim.x * gridDim.y;
    const int lin = blockIdx.y * gridDim.x + blockIdx.x;
    const int swz = (lin & 7) * (nwg >> 3) + (lin >> 3);
    const int bx = swz % gridDim.x, by = swz / gridDim.x;
    const int m0 = by * 128, n0 = bx * 128;

    f32x4 acc[4][4];
#pragma unroll
    for (int i = 0; i < 4; ++i)
#pragma unroll
        for (int j = 0; j < 4; ++j) acc[i][j] = (f32x4){0.f, 0.f, 0.f, 0.f};

    const int srow = tid >> 2;
    const int sseg = tid & 3;
    const int gseg = sseg ^ ((srow >> 1) & 3);
    const int fr = lane & 15, ks = lane >> 4;
    const int rsw = ks ^ ((fr >> 1) & 3);

    auto STAGE = [&](int buf, int k0) {
#pragma unroll
        for (int it = 0; it < 2; ++it) {
            int row = it * 64 + srow;
            const u16* sa = A + (size_t)(m0 + row) * K + k0 + gseg * 8;
            const u16* sw = W + (size_t)(n0 + row) * K + k0 + gseg * 8;
            __builtin_amdgcn_global_load_lds(
                (const __attribute__((address_space(1))) void*)sa,
                (__attribute__((address_space(3))) void*)(&lA[buf][row * 32 + sseg * 8]),
                16, 0, 0);
            __builtin_amdgcn_global_load_lds(
                (const __attribute__((address_space(1))) void*)sw,
                (__attribute__((address_space(3))) void*)(&lB[buf][row * 32 + sseg * 8]),
                16, 0, 0);
        }
    };

    STAGE(0, 0);
    __syncthreads();
    int cur = 0;
    for (int k0 = 0; k0 < K; k0 += 32) {
        if (k0 + 32 < K) STAGE(cur ^ 1, k0 + 32);
        short8 af[4], bfr[4];
#pragma unroll
        for (int i = 0; i < 4; ++i) {
            af[i]  = *(const short8*)(&lA[cur][(wr * 64 + i * 16 + fr) * 32 + rsw * 8]);
            bfr[i] = *(const short8*)(&lB[cur][(wc * 64 + i * 16 + fr) * 32 + rsw * 8]);
        }
#pragma unroll
        for (int i = 0; i < 4; ++i)
#pragma unroll
            for (int j = 0; j < 4; ++j)
                acc[i][j] = __builtin_amdgcn_mfma_f32_16x16x32_bf16(
                    af[i], bfr[j], acc[i][j], 0, 0, 0);
        __syncthreads();
        cur ^= 1;
    }

    const int fq = lane >> 4;
#pragma unroll
    for (int i = 0; i < 4; ++i)
#pragma unroll
        for (int j = 0; j < 4; ++j) {
            int gn = n0 + wc * 64 + j * 16 + fr;
#pragma unroll
            for (int r = 0; r < 4; ++r) {
                int gm = m0 + wr * 64 + i * 16 + fq * 4 + r;
                out[(size_t)gm * N + gn] = acc[i][j][r];
            }
        }
}

// ---------------- Bm / C projections (N=16 each, fp32) ----------------
__global__ __launch_bounds__(256) void bc_kernel(
    const float* __restrict__ x, const float* __restrict__ WB,
    const float* __restrict__ WC, float* __restrict__ Bm, float* __restrict__ Cm) {
    __shared__ float xs[32][65];
    __shared__ float ws[32][65];
    int m0 = blockIdx.x * 32;
    int tid = threadIdx.x;
    int o = tid & 31, mg = tid >> 5;
    float acc[4] = {0.f, 0.f, 0.f, 0.f};
    for (int k0 = 0; k0 < D_; k0 += 64) {
        __syncthreads();
#pragma unroll
        for (int j = 0; j < 8; ++j) {
            int f = j * 256 + tid;
            int r = f >> 6, kk = f & 63;
            xs[r][kk] = x[(size_t)(m0 + r) * D_ + k0 + kk];
            ws[r][kk] = (r < 16) ? WB[(size_t)r * D_ + k0 + kk]
                                 : WC[(size_t)(r - 16) * D_ + k0 + kk];
        }
        __syncthreads();
#pragma unroll 8
        for (int kk = 0; kk < 64; ++kk) {
            float wv = ws[o][kk];
#pragma unroll
            for (int r = 0; r < 4; ++r)
                acc[r] = fmaf(xs[mg * 4 + r][kk], wv, acc[r]);
        }
    }
#pragma unroll
    for (int r = 0; r < 4; ++r) {
        int m = m0 + mg * 4 + r;
        if (o < 16) Bm[(size_t)m * DS_ + o] = acc[r];
        else        Cm[(size_t)m * DS_ + (o - 16)] = acc[r];
    }
}

// ============ chunked scan, thread-owns-d layout ============
// pass 1 — per-chunk decay products P[s] and zero-input responses Z[s]
__global__ __launch_bounds__(256) void scan1_kernel(
    const u16* __restrict__ dt, const u16* __restrict__ xi,
    const float* __restrict__ Bm, const float* __restrict__ A_log,
    float* __restrict__ P, float* __restrict__ Z) {
    const int c = blockIdx.x, dblk = blockIdx.y, b = blockIdx.z;
    const int tid = threadIdx.x;
    const int d = dblk * 256 + tid;
    __shared__ u16 sdt[TT_ * 256];
    __shared__ u16 sxi[TT_ * 256];
    __shared__ float sB[TT_ * 16];
    float A2[16], st[16], Pp[16];
#pragma unroll
    for (int s = 0; s < 16; ++s) {
        A2[s] = -0.5f * __expf(A_log[(size_t)d * DS_ + s]);
        st[s] = 0.f; Pp[s] = 1.f;
    }
    const size_t tb = (size_t)b * T_;
    for (int t0 = c * CL_; t0 < (c + 1) * CL_; t0 += TT_) {
        __syncthreads();
#pragma unroll
        for (int r = 0; r < 4; ++r) {
            int flat = r * 2048 + tid * 8;
            int row = flat >> 8, col = flat & 255;
            const u16* s1 = dt + (tb + t0 + row) * DI_ + dblk * 256 + col;
            const u16* s2 = xi + (tb + t0 + row) * DI_ + dblk * 256 + col;
            __builtin_amdgcn_global_load_lds(
                (const __attribute__((address_space(1))) void*)s1,
                (__attribute__((address_space(3))) void*)(sdt + flat), 16, 0, 0);
            __builtin_amdgcn_global_load_lds(
                (const __attribute__((address_space(1))) void*)s2,
                (__attribute__((address_space(3))) void*)(sxi + flat), 16, 0, 0);
        }
        *(float2*)(sB + tid * 2) = *(const float2*)(Bm + (tb + t0) * DS_ + tid * 2);
        __syncthreads();
#pragma unroll 2
        for (int tt = 0; tt < TT_; ++tt) {
            float dtv = bf2f(sdt[tt * 256 + tid]);
            float xiv = bf2f(sxi[tt * 256 + tid]);
            float dxv = dtv * xiv;
            float bv[16];
            *(float4*)&bv[0]  = *(const float4*)(sB + tt * 16);
            *(float4*)&bv[4]  = *(const float4*)(sB + tt * 16 + 4);
            *(float4*)&bv[8]  = *(const float4*)(sB + tt * 16 + 8);
            *(float4*)&bv[12] = *(const float4*)(sB + tt * 16 + 12);
#pragma unroll
            for (int s = 0; s < 16; ++s) {
                float a2   = fmaf(dtv, -A2[s], 1.f);
                float inv  = __builtin_amdgcn_rcpf(a2);
                float abar = fmaf(2.f, inv, -1.f);
                st[s] = fmaf(abar, st[s], (inv * bv[s]) * dxv);
                Pp[s] *= abar;
            }
        }
    }
    size_t base = (((size_t)b * DI_ + d) * NC_ + c) * 16;
#pragma unroll
    for (int q = 0; q < 4; ++q) {
        *(float4*)(P + base + q * 4) = (float4){Pp[q*4], Pp[q*4+1], Pp[q*4+2], Pp[q*4+3]};
        *(float4*)(Z + base + q * 4) = (float4){st[q*4], st[q*4+1], st[q*4+2], st[q*4+3]};
    }
}

// pass 2 — serial combine over chunks; writes chunk-init states I in-place into P
__global__ __launch_bounds__(256) void scan2_kernel(
    float* __restrict__ P, const float* __restrict__ Z,
    float* __restrict__ st_out) {
    size_t idx = (size_t)blockIdx.x * 256 + threadIdx.x;   // (b*DI+d)*16+s
    size_t bd = idx >> 4;
    int s = (int)(idx & 15);
    float cur = 0.f;
    for (int c = 0; c < NC_; ++c) {
        size_t a = (bd * NC_ + c) * 16 + s;
        float p = P[a], zv = Z[a];
        P[a] = cur;                       // I: state at chunk start
        cur = fmaf(p, cur, zv);
    }
    st_out[idx] = cur;
}

// pass 3 — recompute with init states, emit dot-product outputs
__global__ __launch_bounds__(256) void scan3_kernel(
    const u16* __restrict__ dt, const u16* __restrict__ xi,
    const float* __restrict__ Bm, const float* __restrict__ Cm,
    const float* __restrict__ A_log, const float* __restrict__ I,
    u16* __restrict__ so) {
    const int c = blockIdx.x, dblk = blockIdx.y, b = blockIdx.z;
    const int tid = threadIdx.x;
    const int d = dblk * 256 + tid;
    __shared__ u16 sdt[TT_ * 256];
    __shared__ u16 sxi[TT_ * 256];
    __shared__ float sB[TT_ * 16];
    __shared__ float sC[TT_ * 16];
    float A2[16], st[16];
#pragma unroll
    for (int s = 0; s < 16; ++s)
        A2[s] = -0.5f * __expf(A_log[(size_t)d * DS_ + s]);
    size_t base = (((size_t)b * DI_ + d) * NC_ + c) * 16;
#pragma unroll
    for (int q = 0; q < 4; ++q) {
        float4 v = *(const float4*)(I + base + q * 4);
        st[q*4] = v.x; st[q*4+1] = v.y; st[q*4+2] = v.z; st[q*4+3] = v.w;
    }
    const size_t tb = (size_t)b * T_;
    for (int t0 = c * CL_; t0 < (c + 1) * CL_; t0 += TT_) {
        __syncthreads();
#pragma unroll
        for (int r = 0; r < 4; ++r) {
            int flat = r * 2048 + tid * 8;
            int row = flat >> 8, col = flat & 255;
            const u16* s1 = dt + (tb + t0 + row) * DI_ + dblk * 256 + col;
            const u16* s2 = xi + (tb + t0 + row) * DI_ + dblk * 256 + col;
            __builtin_amdgcn_global_load_lds(
                (const __attribute__((address_space(1))) void*)s1,
                (__attribute__((address_space(3))) void*)(sdt + flat), 16, 0, 0);
            __builtin_amdgcn_global_load_lds(
                (const __attribute__((address_space(1))) void*)s2,
                (__attribute__((address_space(3))) void*)(sxi + flat), 16, 0, 0);
        }
        *(float2*)(sB + tid * 2) = *(const float2*)(Bm + (tb + t0) * DS_ + tid * 2);
        *(float2*)(sC + tid * 2) = *(const float2*)(Cm + (tb + t0) * DS_ + tid * 2);
        __syncthreads();
#pragma unroll 2
        for (int tt = 0; tt < TT_; ++tt) {
            float dtv = bf2f(sdt[tt * 256 + tid]);
            float xiv = bf2f(sxi[tt * 256 + tid]);
            float dxv = dtv * xiv;
            float bv[16], cv[16];
            *(float4*)&bv[0]  = *(const float4*)(sB + tt * 16);
            *(float4*)&bv[4]  = *(const float4*)(sB + tt * 16 + 4);
            *(float4*)&bv[8]  = *(const float4*)(sB + tt * 16 + 8);
            *(float4*)&bv[12] = *(const float4*)(sB + tt * 16 + 12);
            *(float4*)&cv[0]  = *(const float4*)(sC + tt * 16);
            *(float4*)&cv[4]  = *(const float4*)(sC + tt * 16 + 4);
            *(float4*)&cv[8]  = *(const float4*)(sC + tt * 16 + 8);
            *(float4*)&cv[12] = *(const float4*)(sC + tt * 16 + 12);
            float acc = 0.f;
#pragma unroll
            for (int s = 0; s < 16; ++s) {
                float a2   = fmaf(dtv, -A2[s], 1.f);
                float inv  = __builtin_amdgcn_rcpf(a2);
                float abar = fmaf(2.f, inv, -1.f);
                st[s] = fmaf(abar, st[s], (inv * bv[s]) * dxv);
                acc = fmaf(st[s], cv[s], acc);
            }
            so[(tb + t0 + tt) * DI_ + d] = f2bf(acc);
        }
    }
}

// ---------------- gated LayerNorm -> bf16 normed ----------------
__global__ __launch_bounds__(256) void ln_kernel(
    const u16* __restrict__ so, const u16* __restrict__ z,
    const float* __restrict__ gamma, const float* __restrict__ beta,
    u16* __restrict__ normed) {
    int m = blockIdx.x;
    int tid = threadIdx.x;
    size_t base = (size_t)m * DI_;
    float v[8];
    float s = 0.f, s2 = 0.f;
#pragma unroll
    for (int j = 0; j < 8; ++j) {
        int i = tid + j * 256;
        float val = bf2f(so[base + i]) * bf2f(z[base + i]);
        v[j] = val; s += val; s2 += val * val;
    }
#pragma unroll
    for (int off = 32; off; off >>= 1) {
        s  += __shfl_xor(s,  off);
        s2 += __shfl_xor(s2, off);
    }
    __shared__ float rs[4], rq[4];
    int wave = tid >> 6;
    if ((tid & 63) == 0) { rs[wave] = s; rq[wave] = s2; }
    __syncthreads();
    s  = rs[0] + rs[1] + rs[2] + rs[3];
    s2 = rq[0] + rq[1] + rq[2] + rq[3];
    float mu  = s * (1.f / DI_);
    float var = s2 * (1.f / DI_) - mu * mu;
    float rstd = rsqrtf(var + 1e-5f);
#pragma unroll
    for (int j = 0; j < 8; ++j) {
        int i = tid + j * 256;
        float nv = (v[j] - mu) * rstd * gamma[i] + beta[i];
        normed[base + i] = f2bf(nv);
    }
}

extern "C" void kernel_launch(void* const* d_in, const int* in_sizes, int n_in,
                              void* d_out, int out_size, void* d_ws, size_t ws_size,
                              hipStream_t stream) {
    const float* x       = (const float*)d_in[0];
    const float* Win     = (const float*)d_in[1];
    const float* A_log   = (const float*)d_in[2];
    const float* WB      = (const float*)d_in[3];
    const float* WC      = (const float*)d_in[4];
    const float* Wdt     = (const float*)d_in[5];
    const float* bdt     = (const float*)d_in[6];
    const float* dt_bias = (const float*)d_in[7];
    const float* gamma   = (const float*)d_in[8];
    const float* beta    = (const float*)d_in[9];
    const float* Wout    = (const float*)d_in[10];

    float* y_out     = (float*)d_out;
    float* state_out = y_out + (size_t)B_ * T_ * D_;

    char* ws = (char*)d_ws;
    u16* xi_bf   = (u16*)(ws + 0);            // 16 MB
    u16* z_bf    = (u16*)(ws + 16777216);     // 16 MB
    u16* dt_bf   = (u16*)(ws + 33554432);     // 16 MB
    u16* so_bf   = (u16*)(ws + 50331648);     // 16 MB
    u16* nm_bf   = (u16*)(ws + 67108864);     // 16 MB
    u16* x_bf    = (u16*)(ws + 83886080);     // 8 MB  (dead after GEMMs -> P/I)
    u16* win_bf  = (u16*)(ws + 92274688);     // 8 MB  (dead after GEMMs -> Z)
    u16* wdt_bf  = (u16*)(ws + 100663296);    // 4 MB
    u16* wout_bf = (u16*)(ws + 104857600);    // 4 MB
    float* BmB   = (float*)(ws + 109051904);  // 256 KB
    float* CmB   = (float*)(ws + 109314048);  // 256 KB

    // P (8 MB, becomes I in-place) and Z (8 MB) alias dead x_bf / win_bf
    float* Pc = (float*)(ws + 83886080);
    float* Zc = (float*)(ws + 92274688);

    {
        int n4;
        n4 = (B_ * T_ * D_) / 4;
        cvt_kernel<<<(n4 + 255) / 256, 256, 0, stream>>>(x, x_bf, n4);
        n4 = (2 * DI_ * D_) / 4;
        cvt_kernel<<<(n4 + 255) / 256, 256, 0, stream>>>(Win, win_bf, n4);
        n4 = (DI_ * D_) / 4;
        cvt_kernel<<<(n4 + 255) / 256, 256, 0, stream>>>(Wdt, wdt_bf, n4);
        n4 = (D_ * DI_) / 4;
        cvt_kernel<<<(n4 + 255) / 256, 256, 0, stream>>>(Wout, wout_bf, n4);
    }

    dim3 blk(256);
    // fused [xi | z | dt]
    gemm_in<<<dim3(6144 / 128, MROWS / 128), blk, 0, stream>>>(
        x_bf, win_bf, wdt_bf, xi_bf, z_bf, dt_bf, bdt, dt_bias);
    bc_kernel<<<MROWS / 32, 256, 0, stream>>>(x, WB, WC, BmB, CmB);

    // chunked scan (3 passes) — x_bf/win_bf dead from here
    scan1_kernel<<<dim3(NC_, DI_ / 256, B_), blk, 0, stream>>>(
        dt_bf, xi_bf, BmB, A_log, Pc, Zc);
    scan2_kernel<<<(B_ * DI_ * DS_) / 256, blk, 0, stream>>>(
        Pc, Zc, state_out);
    scan3_kernel<<<dim3(NC_, DI_ / 256, B_), blk, 0, stream>>>(
        dt_bf, xi_bf, BmB, CmB, A_log, Pc, so_bf);

    ln_kernel<<<MROWS, 256, 0, stream>>>(so_bf, z_bf, gamma, beta, nm_bf);
    gemm_out<<<dim3(D_ / 128, MROWS / 128), blk, 0, stream>>>(
        nm_bf, wout_bf, y_out, MROWS, D_, DI_);
}